// Round 1
// baseline (12195.695 us; speedup 1.0000x reference)
//
#include <hip/hip_runtime.h>
#include <hip/hip_bf16.h>

// Grouped GRU, fused single-kernel implementation.
// B=32, T=512, G=8, IN=HID=1024, IG=HG=128. 3*HG=384 gate rows per group.
//
// Mapping: one workgroup per (b,g) pair -> 256 workgroups (1 per CU).
// 384 threads: thread o owns gate-row o of W_ih / W_hh (128 weights in VGPRs).
//   o in [0,128): r-gate row o
//   o in [128,256): z-gate row o-128... (actually row o of the stacked 384)
//   o in [256,384): n-gate
// Phase A (per chunk): gx[b,t,g,o] = dot(W_ih[g,o,:], x[b,t,g*128:+128]) + b_ih
//   -> stored to workspace (chunked to fit ws_size).
// Phase B (per chunk): sequential scan; gh = dot(W_hh[g,o,:], h) + b_hh,
//   gates exchanged via tiny LDS buffers, 2 barriers per step.

namespace {
constexpr int GB  = 32;    // batch
constexpr int GT  = 512;   // time
constexpr int GG  = 8;     // groups
constexpr int GIN = 1024;
constexpr int GHID= 1024;
constexpr int GHG = 128;   // hidden per group
constexpr int GO3 = 384;   // 3*HG gate rows
}

__global__ __launch_bounds__(384, 2)
void gru_fused_kernel(const float* __restrict__ x,
                      const float* __restrict__ state,
                      const float* __restrict__ W_ih,
                      const float* __restrict__ W_hh,
                      const float* __restrict__ b_ih,
                      const float* __restrict__ b_hh,
                      float* __restrict__ out,     // [B*T*HID] y, then [G*B*HG] h_out
                      float* __restrict__ gxws,    // scratch: 256 * CS * 384 floats
                      int CS)                      // chunk steps (divides 512, >=4)
{
    const int bg = blockIdx.x;       // 0..255
    const int b  = bg >> 3;          // bg / G
    const int g  = bg & 7;           // bg % G  -> same-g wgs share an XCD (L2 locality for W)
    const int o  = threadIdx.x;      // 0..383

    __shared__ __align__(16) float hbuf[GHG];
    __shared__ __align__(16) float4 xbuf[32][32];   // up to 32 rows x 128 floats (16 KB)
    __shared__ float zbuf[GHG];
    __shared__ float nhbuf[GHG];
    __shared__ float nxbuf[GHG];

    const float bih = b_ih[g * GO3 + o];
    const float bhh = b_hh[g * GO3 + o];

    if (o < GHG) hbuf[o] = state[(g * GB + b) * GHG + o];
    __syncthreads();

    float4 w[32];   // 128 weight floats for this thread's current row

    const int RB  = (CS < 32) ? CS : 32;   // rows staged per LDS batch in phase A
    const int nch = GT / CS;

    for (int c = 0; c < nch; ++c) {
        const int t0 = c * CS;

        // ---------------- Phase A: input-side GEMM for this chunk ----------------
        {
            const float4* wrow = (const float4*)(W_ih + ((size_t)(g * GO3 + o)) * GHG);
            #pragma unroll
            for (int k = 0; k < 32; ++k) w[k] = wrow[k];
        }
        for (int rb = 0; rb < CS; rb += RB) {
            // cooperative stage of RB rows of x (this group's 128-wide slice)
            const int nvec = RB * 32;            // float4s to load
            for (int idx = o; idx < nvec; idx += 384) {
                const int rr = idx >> 5;
                const int k4 = idx & 31;
                const int t  = t0 + rb + rr;
                xbuf[rr][k4] = *(const float4*)(x + ((size_t)(b * GT + t)) * GIN
                                                + g * GHG + (k4 << 2));
            }
            __syncthreads();
            for (int rr = 0; rr < RB; ++rr) {
                const float4* xr = xbuf[rr];   // wave-uniform address -> LDS broadcast
                float acc = bih;
                #pragma unroll
                for (int k = 0; k < 32; ++k) {
                    const float4 xv = xr[k];
                    acc = fmaf(w[k].x, xv.x, acc);
                    acc = fmaf(w[k].y, xv.y, acc);
                    acc = fmaf(w[k].z, xv.z, acc);
                    acc = fmaf(w[k].w, xv.w, acc);
                }
                gxws[((size_t)bg * CS + (rb + rr)) * GO3 + o] = acc;  // coalesced
            }
            __syncthreads();
        }

        // ---------------- Phase B: sequential scan over this chunk ----------------
        {
            const float4* wrow = (const float4*)(W_hh + ((size_t)(g * GO3 + o)) * GHG);
            #pragma unroll
            for (int k = 0; k < 32; ++k) w[k] = wrow[k];
        }
        float gx_next = gxws[((size_t)bg * CS) * GO3 + o];   // prefetch tt=0
        for (int tt = 0; tt < CS; ++tt) {
            const int t = t0 + tt;
            const float gxv = gx_next;
            if (tt + 1 < CS)  // prefetch next step's gx a full step early
                gx_next = gxws[((size_t)bg * CS + (tt + 1)) * GO3 + o];

            const float4* hr = (const float4*)hbuf;  // wave-uniform -> broadcast
            float acc = bhh;
            #pragma unroll
            for (int k = 0; k < 32; ++k) {
                const float4 hv = hr[k];
                acc = fmaf(w[k].x, hv.x, acc);
                acc = fmaf(w[k].y, hv.y, acc);
                acc = fmaf(w[k].z, hv.z, acc);
                acc = fmaf(w[k].w, hv.w, acc);
            }
            // acc = gh row-o (incl. b_hh). Exchange gate pieces via LDS.
            const float pre = gxv + acc;
            float r = 0.f;
            if (o >= 256) {               // n-gate rows: publish gh_n and gx_n
                nhbuf[o - 256] = acc;
                nxbuf[o - 256] = gxv;
            } else if (o >= 128) {        // z-gate rows
                zbuf[o - 128] = 1.f / (1.f + expf(-pre));
            } else {                      // r-gate rows: keep r in register
                r = 1.f / (1.f + expf(-pre));
            }
            __syncthreads();
            if (o < GHG) {
                const float n  = tanhf(nxbuf[o] + r * nhbuf[o]);
                const float z  = zbuf[o];
                const float hp = hbuf[o];
                const float hn = fmaf(z, hp - n, n);   // (1-z)*n + z*h
                hbuf[o] = hn;                           // only thread o touches h[o]
                out[((size_t)(b * GT + t)) * GHID + g * GHG + o] = hn;
            }
            __syncthreads();
        }
    }

    // final hidden state: [G,B,HG] appended after y
    if (o < GHG) {
        out[(size_t)GB * GT * GHID + ((size_t)g * GB + b) * GHG + o] = hbuf[o];
    }
}

extern "C" void kernel_launch(void* const* d_in, const int* in_sizes, int n_in,
                              void* d_out, int out_size, void* d_ws, size_t ws_size,
                              hipStream_t stream) {
    const float* x     = (const float*)d_in[0];
    const float* state = (const float*)d_in[1];
    const float* W_ih  = (const float*)d_in[2];
    const float* W_hh  = (const float*)d_in[3];
    const float* b_ih  = (const float*)d_in[4];
    const float* b_hh  = (const float*)d_in[5];
    float* out = (float*)d_out;

    // Pick largest chunk (in timesteps) whose gx scratch fits in ws:
    // bytes = 256 wgs * CS * 384 floats * 4
    int CS = 4;
    for (int cand = 512; cand >= 4; cand >>= 1) {
        const size_t need = (size_t)256 * cand * 384 * 4;
        if (need <= ws_size) { CS = cand; break; }
    }

    gru_fused_kernel<<<dim3(256), dim3(384), 0, stream>>>(
        x, state, W_ih, W_hh, b_ih, b_hh, out, (float*)d_ws, CS);
}

// Round 4
// 2373.982 us; speedup vs baseline: 5.1372x; 5.1372x over previous
//
#include <hip/hip_runtime.h>
#include <hip/hip_bf16.h>

// Grouped GRU, fused single-kernel implementation.
// B=32, T=512, G=8, IN=HID=1024, IG=HG=128. 3*HG=384 gate rows per group.
//
// Mapping: one workgroup per (b,g) pair -> 256 workgroups (1 per CU).
// 384 threads: thread o owns gate-row o of W_ih / W_hh (128 floats in VGPRs).
// Phase A (per chunk): gx = x . W_ih^T + b_ih  -> workspace (chunked to ws_size)
// Phase B (per chunk): sequential scan; gh = W_hh . h + b_hh, gates exchanged
//   via tiny LDS buffers, 2 barriers per step. h broadcast via LDS (wave-uniform
//   ds_read_b128 -> no bank conflicts).
//
// Round-2 fix: launch_bounds(384,1) + asm register pin so the 128 weight floats
// actually stay in VGPRs (round 1: compiler sank weight loads into the t-loop ->
// 21 GB HBM fetch, 12.2 ms).

namespace {
constexpr int GB  = 32;    // batch
constexpr int GT  = 512;   // time
constexpr int GG  = 8;     // groups
constexpr int GIN = 1024;
constexpr int GHID= 1024;
constexpr int GHG = 128;   // hidden per group
constexpr int GO3 = 384;   // 3*HG gate rows
}

__device__ __forceinline__ void pin4(float4& v) {
    asm volatile("" : "+v"(v.x), "+v"(v.y), "+v"(v.z), "+v"(v.w));
}

__global__ __launch_bounds__(384, 1)
void gru_fused_kernel(const float* __restrict__ x,
                      const float* __restrict__ state,
                      const float* __restrict__ W_ih,
                      const float* __restrict__ W_hh,
                      const float* __restrict__ b_ih,
                      const float* __restrict__ b_hh,
                      float* __restrict__ out,     // [B*T*HID] y, then [G*B*HG] h_out
                      float* __restrict__ gxws,    // scratch: 256 * CS * 384 floats
                      int CS)                      // chunk steps (divides 512, >=4)
{
    const int bg = blockIdx.x;       // 0..255
    const int b  = bg >> 3;          // bg / G
    const int g  = bg & 7;           // bg % G  -> same-g wgs share an XCD (L2 locality for W)
    const int o  = threadIdx.x;      // 0..383 (wave 0-1: r rows, 2-3: z rows, 4-5: n rows)

    __shared__ __align__(16) float hbuf[GHG];
    __shared__ __align__(16) float4 xbuf[32][32];   // up to 32 rows x 128 floats (16 KB)
    __shared__ float zbuf[GHG];
    __shared__ float nhbuf[GHG];
    __shared__ float nxbuf[GHG];

    const float bih = b_ih[g * GO3 + o];
    const float bhh = b_hh[g * GO3 + o];

    if (o < GHG) hbuf[o] = state[(g * GB + b) * GHG + o];
    __syncthreads();

    float4 w[32];   // 128 weight floats for this thread's current row (pinned in VGPRs)

    const int RB  = (CS < 32) ? CS : 32;   // rows staged per LDS batch in phase A
    const int nch = GT / CS;

    for (int c = 0; c < nch; ++c) {
        const int t0 = c * CS;

        // ---------------- Phase A: input-side GEMM for this chunk ----------------
        {
            const float4* wrow = (const float4*)(W_ih + ((size_t)(g * GO3 + o)) * GHG);
            #pragma unroll
            for (int k = 0; k < 32; ++k) w[k] = wrow[k];
            #pragma unroll
            for (int k = 0; k < 32; ++k) pin4(w[k]);   // force VGPR residency
        }
        for (int rb = 0; rb < CS; rb += RB) {
            const int nvec = RB * 32;            // float4s to stage
            for (int idx = o; idx < nvec; idx += 384) {
                const int rr = idx >> 5;
                const int k4 = idx & 31;
                const int t  = t0 + rb + rr;
                xbuf[rr][k4] = *(const float4*)(x + ((size_t)(b * GT + t)) * GIN
                                                + g * GHG + (k4 << 2));
            }
            __syncthreads();
            for (int rr = 0; rr < RB; ++rr) {
                const float4* xr = xbuf[rr];   // wave-uniform address -> LDS broadcast
                float a0 = 0.f, a1 = 0.f, a2 = 0.f, a3 = 0.f;
                #pragma unroll
                for (int k = 0; k < 32; ++k) {
                    const float4 xv = xr[k];
                    a0 = fmaf(w[k].x, xv.x, a0);
                    a1 = fmaf(w[k].y, xv.y, a1);
                    a2 = fmaf(w[k].z, xv.z, a2);
                    a3 = fmaf(w[k].w, xv.w, a3);
                }
                gxws[((size_t)bg * CS + (rb + rr)) * GO3 + o] =
                    bih + ((a0 + a1) + (a2 + a3));          // coalesced
            }
            __syncthreads();
        }

        // ---------------- Phase B: sequential scan over this chunk ----------------
        {
            const float4* wrow = (const float4*)(W_hh + ((size_t)(g * GO3 + o)) * GHG);
            #pragma unroll
            for (int k = 0; k < 32; ++k) w[k] = wrow[k];
            #pragma unroll
            for (int k = 0; k < 32; ++k) pin4(w[k]);   // force VGPR residency
        }
        float gx_next = gxws[((size_t)bg * CS) * GO3 + o];   // prefetch tt=0
        for (int tt = 0; tt < CS; ++tt) {
            const int t = t0 + tt;
            const float gxv = gx_next;
            if (tt + 1 < CS)  // prefetch next step's gx a full step early
                gx_next = gxws[((size_t)bg * CS + (tt + 1)) * GO3 + o];

            const float4* hr = (const float4*)hbuf;  // wave-uniform -> broadcast
            float a0 = 0.f, a1 = 0.f, a2 = 0.f, a3 = 0.f;
            #pragma unroll
            for (int k = 0; k < 32; ++k) {
                const float4 hv = hr[k];
                a0 = fmaf(w[k].x, hv.x, a0);
                a1 = fmaf(w[k].y, hv.y, a1);
                a2 = fmaf(w[k].z, hv.z, a2);
                a3 = fmaf(w[k].w, hv.w, a3);
            }
            const float acc = bhh + ((a0 + a1) + (a2 + a3));  // gh row o
            const float pre = gxv + acc;
            float r = 0.f;
            if (o >= 256) {               // n-gate rows: publish gh_n and gx_n
                nhbuf[o - 256] = acc;
                nxbuf[o - 256] = gxv;
            } else if (o >= 128) {        // z-gate rows
                zbuf[o - 128] = 1.f / (1.f + expf(-pre));
            } else {                      // r-gate rows: keep r in register
                r = 1.f / (1.f + expf(-pre));
            }
            __syncthreads();
            if (o < GHG) {
                const float n  = tanhf(nxbuf[o] + r * nhbuf[o]);
                const float z  = zbuf[o];
                const float hp = hbuf[o];
                const float hn = fmaf(z, hp - n, n);   // (1-z)*n + z*h
                hbuf[o] = hn;                           // only thread o touches h[o]
                out[((size_t)(b * GT + t)) * GHID + g * GHG + o] = hn;
            }
            __syncthreads();
        }
    }

    // final hidden state: [G,B,HG] appended after y
    if (o < GHG) {
        out[(size_t)GB * GT * GHID + ((size_t)g * GB + b) * GHG + o] = hbuf[o];
    }
}

extern "C" void kernel_launch(void* const* d_in, const int* in_sizes, int n_in,
                              void* d_out, int out_size, void* d_ws, size_t ws_size,
                              hipStream_t stream) {
    const float* x     = (const float*)d_in[0];
    const float* state = (const float*)d_in[1];
    const float* W_ih  = (const float*)d_in[2];
    const float* W_hh  = (const float*)d_in[3];
    const float* b_ih  = (const float*)d_in[4];
    const float* b_hh  = (const float*)d_in[5];
    float* out = (float*)d_out;

    // Largest chunk (timesteps) whose gx scratch fits in ws:
    // bytes = 256 wgs * CS * 384 floats * 4
    int CS = 4;
    for (int cand = 512; cand >= 4; cand >>= 1) {
        const size_t need = (size_t)256 * cand * 384 * 4;
        if (need <= ws_size) { CS = cand; break; }
    }

    gru_fused_kernel<<<dim3(256), dim3(384), 0, stream>>>(
        x, state, W_ih, W_hh, b_ih, b_hh, out, (float*)d_ws, CS);
}

// Round 6
// 828.796 us; speedup vs baseline: 14.7150x; 2.8644x over previous
//
#include <hip/hip_runtime.h>
#include <hip/hip_bf16.h>

// Grouped GRU, fused single-kernel. B=32,T=512,G=8,IN=HID=1024,IG=HG=128.
//
// Round-5 redesign: 512 threads/wg, lane (j,kq): j=w*16+(l&15), kq=l>>4.
// Each lane holds the kq-slice (32 floats) of weight rows {j,128+j,256+j}
// (r,z,n gates) = 96 weight floats = 24 float4 -> fits VGPR budget (256 @ 8
// waves) WITHOUT spilling (round 4: 128 floats/lane spilled to scratch ->
// L2 re-stream every step, 2.37 ms).
// Partial k-dots combined in-wave via shfl_xor(16,32); gates computed fully
// in-lane -> ONE barrier per timestep (double-buffered h in LDS).
// CS=32 chunking keeps gxws L2-resident (2 MB/XCD).

namespace {
constexpr int GB  = 32;
constexpr int GT  = 512;
constexpr int GIN = 1024;
constexpr int GHID= 1024;
constexpr int GHG = 128;
constexpr int GO3 = 384;
constexpr int PADK   = 40;            // 32 data + 8 pad floats per kq block
constexpr int ROWSTR = 4 * PADK;      // 160 floats per padded 128-float row
constexpr int RBMAX  = 16;            // x rows staged per LDS batch
}

__device__ __forceinline__ void pinf4(float4& v) {
    asm volatile("" : "+v"(v.x), "+v"(v.y), "+v"(v.z), "+v"(v.w));
}
__device__ __forceinline__ float sigm(float x) {
    return __builtin_amdgcn_rcpf(1.f + __expf(-x));
}
__device__ __forceinline__ float tanh_fast(float x) {
    // 1 - 2/(e^{2x}+1); saturates correctly for |x| large
    return 1.f - 2.f * __builtin_amdgcn_rcpf(__expf(2.f * x) + 1.f);
}

__global__ __launch_bounds__(512, 2)
void gru_fused_kernel(const float* __restrict__ x,
                      const float* __restrict__ state,
                      const float* __restrict__ W_ih,
                      const float* __restrict__ W_hh,
                      const float* __restrict__ b_ih,
                      const float* __restrict__ b_hh,
                      float* __restrict__ out,    // [B*T*HID] y, then [G*B*HG]
                      float* __restrict__ gxws,   // [256][CS][128][4]
                      int CS)
{
    const int bg = blockIdx.x;        // 0..255
    const int b  = bg >> 3;
    const int g  = bg & 7;            // bg%8 -> same-g wgs share an XCD (L2 locality)
    const int tid= threadIdx.x;
    const int w  = tid >> 6;          // wave 0..7
    const int l  = tid & 63;
    const int j  = (w << 4) | (l & 15);   // hidden row 0..127
    const int kq = l >> 4;                // k-quarter 0..3
    const bool kq0 = (kq == 0);

    __shared__ __align__(16) float xlds[RBMAX * ROWSTR]; // 10.2 KB
    __shared__ __align__(16) float hlds[2][ROWSTR];      // 1.3 KB, double-buffered

    // biases for this lane's rows
    const float bir = b_ih[g * GO3 + j];
    const float biz = b_ih[g * GO3 + 128 + j];
    const float bin = b_ih[g * GO3 + 256 + j];
    const float bhr = b_hh[g * GO3 + j];
    const float bhz = b_hh[g * GO3 + 128 + j];
    const float bhn = b_hh[g * GO3 + 256 + j];

    const int jblk = (j >> 5) * PADK + (j & 31);  // padded position of h[j]

    if (l < 16) {   // 8 waves x 16 lanes = 128 writers cover j=0..127
        hlds[0][jblk] = state[(g * GB + b) * GHG + j];
    }
    __syncthreads();

    float4 wr[8], wz[8], wn[8];   // 96 weight floats, VGPR-resident

    const int nch = GT / CS;
    int hp = 0;

    for (int c = 0; c < nch; ++c) {
        const int t0 = c * CS;

        // ================= Phase A: gx for this chunk =================
        {
            const size_t gb = (size_t)g * GO3 * GHG;
            const float4* pr = (const float4*)(W_ih + gb + (size_t)(j      ) * GHG + kq * 32);
            const float4* pz = (const float4*)(W_ih + gb + (size_t)(j + 128) * GHG + kq * 32);
            const float4* pn = (const float4*)(W_ih + gb + (size_t)(j + 256) * GHG + kq * 32);
            #pragma unroll
            for (int f = 0; f < 8; ++f) { wr[f] = pr[f]; wz[f] = pz[f]; wn[f] = pn[f]; }
            #pragma unroll
            for (int f = 0; f < 8; ++f) { pinf4(wr[f]); pinf4(wz[f]); pinf4(wn[f]); }
        }
        for (int rb = 0; rb < CS; rb += RBMAX) {
            const int rows = (CS - rb < RBMAX) ? (CS - rb) : RBMAX;
            // stage rows of x (group slice) into padded LDS layout
            const int nf4 = rows * 32;
            for (int idx = tid; idx < nf4; idx += 512) {
                const int rr = idx >> 5;
                const int f4 = idx & 31;            // float4 index within 128 floats
                const int kqs = f4 >> 3;
                const int off = (f4 & 7) << 2;      // float offset inside kq block
                const float4 v = *(const float4*)(x + ((size_t)(b * GT + t0 + rb + rr)) * GIN
                                                  + g * GHG + (f4 << 2));
                *(float4*)&xlds[rr * ROWSTR + kqs * PADK + off] = v;
            }
            __syncthreads();
            for (int rr = 0; rr < rows; ++rr) {
                const float4* xr = (const float4*)&xlds[rr * ROWSTR + kq * PADK];
                float r0 = 0.f, r1 = 0.f, z0 = 0.f, z1 = 0.f, n0 = 0.f, n1 = 0.f;
                #pragma unroll
                for (int f = 0; f < 8; ++f) {
                    const float4 xv = xr[f];
                    r0 = fmaf(wr[f].x, xv.x, r0); r1 = fmaf(wr[f].y, xv.y, r1);
                    z0 = fmaf(wz[f].x, xv.x, z0); z1 = fmaf(wz[f].y, xv.y, z1);
                    n0 = fmaf(wn[f].x, xv.x, n0); n1 = fmaf(wn[f].y, xv.y, n1);
                    r0 = fmaf(wr[f].z, xv.z, r0); r1 = fmaf(wr[f].w, xv.w, r1);
                    z0 = fmaf(wz[f].z, xv.z, z0); z1 = fmaf(wz[f].w, xv.w, z1);
                    n0 = fmaf(wn[f].z, xv.z, n0); n1 = fmaf(wn[f].w, xv.w, n1);
                }
                float ar = r0 + r1, az = z0 + z1, an = n0 + n1;
                ar += __shfl_xor(ar, 16); ar += __shfl_xor(ar, 32);
                az += __shfl_xor(az, 16); az += __shfl_xor(az, 32);
                an += __shfl_xor(an, 16); an += __shfl_xor(an, 32);
                if (kq0) {
                    float4 o4 = make_float4(ar + bir, az + biz, an + bin, 0.f);
                    *(float4*)(gxws + (((size_t)bg * CS + (rb + rr)) * GHG + j) * 4) = o4;
                }
            }
            __syncthreads();
        }

        // ================= Phase B: recurrent scan =================
        {
            const size_t gb = (size_t)g * GO3 * GHG;
            const float4* pr = (const float4*)(W_hh + gb + (size_t)(j      ) * GHG + kq * 32);
            const float4* pz = (const float4*)(W_hh + gb + (size_t)(j + 128) * GHG + kq * 32);
            const float4* pn = (const float4*)(W_hh + gb + (size_t)(j + 256) * GHG + kq * 32);
            #pragma unroll
            for (int f = 0; f < 8; ++f) { wr[f] = pr[f]; wz[f] = pz[f]; wn[f] = pn[f]; }
            #pragma unroll
            for (int f = 0; f < 8; ++f) { pinf4(wr[f]); pinf4(wz[f]); pinf4(wn[f]); }
        }
        float4 gx4 = *(const float4*)(gxws + (((size_t)bg * CS) * GHG + j) * 4);
        for (int tt = 0; tt < CS; ++tt) {
            const float4 gxv = gx4;
            if (tt + 1 < CS)   // prefetch next step's gx (L2-resident)
                gx4 = *(const float4*)(gxws + (((size_t)bg * CS + tt + 1) * GHG + j) * 4);

            const float4* hr = (const float4*)&hlds[hp][kq * PADK];
            const float hold = hlds[hp][jblk];
            float r0 = 0.f, r1 = 0.f, z0 = 0.f, z1 = 0.f, n0 = 0.f, n1 = 0.f;
            #pragma unroll
            for (int f = 0; f < 8; ++f) {
                const float4 hv = hr[f];
                r0 = fmaf(wr[f].x, hv.x, r0); r1 = fmaf(wr[f].y, hv.y, r1);
                z0 = fmaf(wz[f].x, hv.x, z0); z1 = fmaf(wz[f].y, hv.y, z1);
                n0 = fmaf(wn[f].x, hv.x, n0); n1 = fmaf(wn[f].y, hv.y, n1);
                r0 = fmaf(wr[f].z, hv.z, r0); r1 = fmaf(wr[f].w, hv.w, r1);
                z0 = fmaf(wz[f].z, hv.z, z0); z1 = fmaf(wz[f].w, hv.w, z1);
                n0 = fmaf(wn[f].z, hv.z, n0); n1 = fmaf(wn[f].w, hv.w, n1);
            }
            float ar = r0 + r1, az = z0 + z1, an = n0 + n1;
            ar += __shfl_xor(ar, 16); ar += __shfl_xor(ar, 32);
            az += __shfl_xor(az, 16); az += __shfl_xor(az, 32);
            an += __shfl_xor(an, 16); an += __shfl_xor(an, 32);

            const float r  = sigm(gxv.x + ar + bhr);
            const float z  = sigm(gxv.y + az + bhz);
            const float n  = tanh_fast(gxv.z + r * (an + bhn));
            const float hn = fmaf(z, hold - n, n);       // (1-z)*n + z*h

            if (kq0) {
                hlds[hp ^ 1][jblk] = hn;
                out[((size_t)(b * GT + t0 + tt)) * GHID + g * GHG + j] = hn;
            }
            __syncthreads();
            hp ^= 1;
        }
    }

    if (l < 16) {   // final hidden state [G,B,HG]
        out[(size_t)GB * GT * GHID + ((size_t)g * GB + b) * GHG + j] = hlds[hp][jblk];
    }
}

extern "C" void kernel_launch(void* const* d_in, const int* in_sizes, int n_in,
                              void* d_out, int out_size, void* d_ws, size_t ws_size,
                              hipStream_t stream) {
    const float* x     = (const float*)d_in[0];
    const float* state = (const float*)d_in[1];
    const float* W_ih  = (const float*)d_in[2];
    const float* W_hh  = (const float*)d_in[3];
    const float* b_ih  = (const float*)d_in[4];
    const float* b_hh  = (const float*)d_in[5];
    float* out = (float*)d_out;

    // gxws bytes = 256 wgs * CS * 128 * 4 floats * 4B; CS=32 -> 16.8 MB (L2-resident/XCD)
    int CS = 8;
    for (int cand = 32; cand >= 8; cand >>= 1) {
        const size_t need = (size_t)256 * cand * GHG * 4 * 4;
        if (need <= ws_size) { CS = cand; break; }
    }

    gru_fused_kernel<<<dim3(256), dim3(512), 0, stream>>>(
        x, state, W_ih, W_hh, b_ih, b_hh, out, (float*)d_ws, CS);
}

// Round 7
// 373.732 us; speedup vs baseline: 32.6322x; 2.2176x over previous
//
#include <hip/hip_runtime.h>
#include <hip/hip_bf16.h>

// Grouped GRU via MFMA (fp16 inputs, fp32 accumulate). B=32,T=512,G=8,HG=128.
// One wg per (b,g): 256 wgs = 1/CU. 8 waves; wave w owns M-tiles {w,w+8,w+16}
// = gate rows 16w..16w+15 of r/z/n. Weights live in VGPRs as f16 A-fragments
// for the ENTIRE kernel (48+48 VGPRs, loaded once).
//
// Phase A (per 32-t chunk): gx[t][384] = W_ih . x_t via mfma_f32_16x16x32_f16,
//   N=16 real timestep columns per MFMA. +b_ih, fp32 -> gxws.
// Phase B: per step, broadcast h (fp16, LDS) into every lane's B-fragment ->
//   every output column equals gh = W_hh . h (rank-1 trick: no shuffles, the
//   MFMA does the K-reduction). Lanes c<4 compute gates for j=16w+4q+c fully
//   in-lane (master h fp32 in registers), write h16 + y. 1 barrier/step.
//
// Fragment layouts (gfx950 16x16x32): A[m=l&15][k=(l>>4)*8+i],
// B[k=(l>>4)*8+i][n=l&15], D[m=(l>>4)*4+r][n=l&15] (C/D verified in guide).

typedef _Float16 half8 __attribute__((ext_vector_type(8)));
typedef float f32x4 __attribute__((ext_vector_type(4)));

namespace {
constexpr int GB = 32, GT = 512, GIN = 1024, GHID = 1024, GHG = 128, GO3 = 384;
constexpr int XPAD = 136;   // fp16 elems per padded x row (128+8): 2-way banks
constexpr int CS   = 32;    // timesteps per chunk; gxws = 256*32*384*4B = 12.6 MB
}

__device__ __forceinline__ float sigm(float x) {
    return __builtin_amdgcn_rcpf(1.f + __expf(-x));
}
__device__ __forceinline__ float tanh_fast(float x) {
    return 1.f - 2.f * __builtin_amdgcn_rcpf(__expf(2.f * x) + 1.f);
}
__device__ __forceinline__ float sel4(f32x4 a, int c) {   // a[c], c in 0..3
    float v = (c == 1) ? a.y : a.x;
    v = (c == 2) ? a.z : v;
    return (c == 3) ? a.w : v;
}
__device__ __forceinline__ half8 cvt8(const float* p) {
    float4 v0 = *(const float4*)p;
    float4 v1 = *(const float4*)(p + 4);
    half8 f;
    f[0] = (_Float16)v0.x; f[1] = (_Float16)v0.y; f[2] = (_Float16)v0.z; f[3] = (_Float16)v0.w;
    f[4] = (_Float16)v1.x; f[5] = (_Float16)v1.y; f[6] = (_Float16)v1.z; f[7] = (_Float16)v1.w;
    return f;
}

__global__ __launch_bounds__(512, 2)
void gru_mfma_kernel(const float* __restrict__ x,
                     const float* __restrict__ state,
                     const float* __restrict__ W_ih,
                     const float* __restrict__ W_hh,
                     const float* __restrict__ b_ih,
                     const float* __restrict__ b_hh,
                     float* __restrict__ out,     // [B*T*HID] y, then [G*B*HG]
                     float* __restrict__ gxws)    // [256][CS][384] fp32
{
    const int bg = blockIdx.x;          // 0..255
    const int b  = bg >> 3;
    const int g  = bg & 7;              // same-g wgs share an XCD (L2 for W)
    const int tid = threadIdx.x;
    const int w  = tid >> 6;            // wave 0..7
    const int l  = tid & 63;
    const int q  = l >> 4;              // 0..3
    const int c  = l & 15;              // 0..15

    __shared__ __align__(16) _Float16 x16[32 * XPAD];  // 8.5 KB
    __shared__ __align__(16) _Float16 h16[2][GHG];     // 512 B, double-buffered

    // ---- weights as f16 A-fragments, resident for the whole kernel ----
    half8 wih[3][4], whh[3][4];         // [gate][ktile]; 96 VGPRs total
    {
        const float* WI = W_ih + (size_t)g * GO3 * GHG;
        const float* WH = W_hh + (size_t)g * GO3 * GHG;
        #pragma unroll
        for (int G = 0; G < 3; ++G) {
            const int row = G * 128 + 16 * w + c;     // A: m = l&15
            #pragma unroll
            for (int kt = 0; kt < 4; ++kt) {
                const int ko = kt * 32 + q * 8;       // A: k = (l>>4)*8+i
                wih[G][kt] = cvt8(WI + (size_t)row * GHG + ko);
                whh[G][kt] = cvt8(WH + (size_t)row * GHG + ko);
            }
        }
    }

    // phase-A biases: rows 16w+4q+0..3 per gate (match D rows)
    f32x4 biA[3];
    #pragma unroll
    for (int G = 0; G < 3; ++G)
        biA[G] = *(const f32x4*)(b_ih + g * GO3 + G * 128 + 16 * w + 4 * q);

    // phase-B per-lane state (lanes c<4 own hidden row j = 16w+4q+c)
    const int jrow = 16 * w + 4 * q + c;
    float bhr = 0.f, bhz = 0.f, bhn = 0.f, hmst = 0.f;
    if (c < 4) {
        bhr  = b_hh[g * GO3 + jrow];
        bhz  = b_hh[g * GO3 + 128 + jrow];
        bhn  = b_hh[g * GO3 + 256 + jrow];
        hmst = state[(g * GB + b) * GHG + jrow];
    }
    if (tid < GHG) h16[0][tid] = (_Float16)state[(g * GB + b) * GHG + tid];
    __syncthreads();

    int hp = 0;
    for (int ch = 0; ch < GT / CS; ++ch) {
        const int t0 = ch * CS;

        // ================= Phase A: gx for 32 timesteps =================
        {   // stage x[t0..t0+31][128] -> fp16 LDS (padded rows)
            const int tt = tid >> 4;              // 0..31
            const int k8 = (tid & 15) * 8;
            const float* px = x + ((size_t)(b * GT + t0 + tt)) * GIN + g * GHG + k8;
            *(half8*)&x16[tt * XPAD + k8] = cvt8(px);
        }
        __syncthreads();
        #pragma unroll
        for (int nt = 0; nt < 2; ++nt) {          // 2 N-tiles of 16 t
            half8 xf[4];
            #pragma unroll
            for (int kt = 0; kt < 4; ++kt)        // B: k=(l>>4)*8+i, n=l&15 (=t)
                xf[kt] = *(const half8*)&x16[(nt * 16 + c) * XPAD + kt * 32 + q * 8];
            #pragma unroll
            for (int G = 0; G < 3; ++G) {
                f32x4 acc = {0.f, 0.f, 0.f, 0.f};
                #pragma unroll
                for (int kt = 0; kt < 4; ++kt)
                    acc = __builtin_amdgcn_mfma_f32_16x16x32_f16(wih[G][kt], xf[kt], acc, 0, 0, 0);
                f32x4 o = acc + biA[G];           // rows 16w+4q+0..3, t = t0+nt*16+c
                *(f32x4*)(gxws + ((size_t)bg * CS + nt * 16 + c) * GO3
                          + G * 128 + 16 * w + 4 * q) = o;
            }
        }
        __syncthreads();

        // ================= Phase B: 32 recurrent steps =================
        float gxr = 0.f, gxz = 0.f, gxn = 0.f;
        if (c < 4) {   // prefetch gx for tt=0
            const float* p = gxws + (size_t)bg * CS * GO3;
            gxr = p[jrow]; gxz = p[128 + jrow]; gxn = p[256 + jrow];
        }
        for (int tt = 0; tt < CS; ++tt) {
            half8 hf[4];
            #pragma unroll
            for (int kt = 0; kt < 4; ++kt)        // broadcast: B[k][n] = h[k] for all n
                hf[kt] = *(const half8*)&h16[hp][kt * 32 + q * 8];
            f32x4 aR = {0.f,0.f,0.f,0.f}, aZ = {0.f,0.f,0.f,0.f}, aN = {0.f,0.f,0.f,0.f};
            #pragma unroll
            for (int kt = 0; kt < 4; ++kt) {
                aR = __builtin_amdgcn_mfma_f32_16x16x32_f16(whh[0][kt], hf[kt], aR, 0, 0, 0);
                aZ = __builtin_amdgcn_mfma_f32_16x16x32_f16(whh[1][kt], hf[kt], aZ, 0, 0, 0);
                aN = __builtin_amdgcn_mfma_f32_16x16x32_f16(whh[2][kt], hf[kt], aN, 0, 0, 0);
            }
            const float cr = gxr, cz = gxz, cn = gxn;
            if (c < 4 && tt + 1 < CS) {           // prefetch next step's gx (L2)
                const float* p = gxws + ((size_t)bg * CS + tt + 1) * GO3;
                gxr = p[jrow]; gxz = p[128 + jrow]; gxn = p[256 + jrow];
            }
            if (c < 4) {                          // every column of D equals gh
                const float ghr = sel4(aR, c), ghz = sel4(aZ, c), ghn = sel4(aN, c);
                const float r  = sigm(cr + ghr + bhr);
                const float z  = sigm(cz + ghz + bhz);
                const float n  = tanh_fast(cn + r * (ghn + bhn));
                const float hn = n + z * (hmst - n);   // (1-z)*n + z*h
                hmst = hn;
                h16[hp ^ 1][jrow] = (_Float16)hn;
                out[((size_t)(b * GT + t0 + tt)) * GHID + g * GHG + jrow] = hn;
            }
            __syncthreads();
            hp ^= 1;
        }
    }

    if (c < 4)   // final hidden state [G,B,HG]
        out[(size_t)GB * GT * GHID + ((size_t)g * GB + b) * GHG + jrow] = hmst;
}

extern "C" void kernel_launch(void* const* d_in, const int* in_sizes, int n_in,
                              void* d_out, int out_size, void* d_ws, size_t ws_size,
                              hipStream_t stream) {
    const float* x     = (const float*)d_in[0];
    const float* state = (const float*)d_in[1];
    const float* W_ih  = (const float*)d_in[2];
    const float* W_hh  = (const float*)d_in[3];
    const float* b_ih  = (const float*)d_in[4];
    const float* b_hh  = (const float*)d_in[5];
    float* out = (float*)d_out;
    // gxws: 256 * 32 * 384 * 4B = 12.6 MB (round 6 proved ws >= 16.8 MB)
    gru_mfma_kernel<<<dim3(256), dim3(512), 0, stream>>>(
        x, state, W_ih, W_hh, b_ih, b_hh, out, (float*)d_ws);
}